// Round 14
// baseline (157.905 us; speedup 1.0000x reference)
//
#include <hip/hip_runtime.h>
#include <math.h>

#define NB 32
#define LQ 2048
#define LK 2048
#define HD 1024
#define AD 512
#define QCH 64   // q-chunks for first-stage query reduction (2048 stream blocks)

typedef float vf4 __attribute__((ext_vector_type(4)));

// =====================================================================
// K1: blocks 0..2047   : partial[qc][b][h] = sum over 32-row q-chunk
//                        (4 rows in flight, non-temporal loads)
//     blocks 2048..2063: wv_eff[h] = Wk[h,:]·Wv (wave-per-row)
//     block  2064      : c_v = bk·Wv + bv
// (round-13 proven)
// =====================================================================
__global__ void __launch_bounds__(256)
k1_stream(const float* __restrict__ query, const float* __restrict__ Wk,
          const float* __restrict__ Wv, const float* __restrict__ bk,
          const float* __restrict__ bv, float* __restrict__ partial,
          float* __restrict__ wv_eff, float* __restrict__ c_v) {
    const int bid = blockIdx.x;
    const int t = threadIdx.x;
    if (bid < NB * QCH) {
        int b = bid / QCH, qc = bid % QCH;
        const int QPC = LQ / QCH;        // 32 rows per chunk
        vf4 a0 = {0.f,0.f,0.f,0.f}, a1 = {0.f,0.f,0.f,0.f};
        vf4 a2 = {0.f,0.f,0.f,0.f}, a3 = {0.f,0.f,0.f,0.f};
        const vf4* src = (const vf4*)(query + ((size_t)b * LQ + (size_t)qc * QPC) * HD);
        for (int q = 0; q < QPC; q += 4) {
            vf4 v0 = __builtin_nontemporal_load(&src[(size_t)(q + 0) * (HD / 4) + t]);
            vf4 v1 = __builtin_nontemporal_load(&src[(size_t)(q + 1) * (HD / 4) + t]);
            vf4 v2 = __builtin_nontemporal_load(&src[(size_t)(q + 2) * (HD / 4) + t]);
            vf4 v3 = __builtin_nontemporal_load(&src[(size_t)(q + 3) * (HD / 4) + t]);
            a0 += v0; a1 += v1; a2 += v2; a3 += v3;
        }
        vf4 acc = (a0 + a1) + (a2 + a3);
        ((vf4*)(partial + ((size_t)qc * NB + b) * HD))[t] = acc;
    } else if (bid < NB * QCH + 16) {
        int w = t >> 6, lane = t & 63;
        int gw = (bid - NB * QCH) * 4 + w;           // 0..63
        const float4* vv = (const float4*)Wv;
        for (int r = 0; r < 16; ++r) {
            int h = gw * 16 + r;
            const float4* wr = (const float4*)(Wk + (size_t)h * AD);
            double acc = 0.0;
            #pragma unroll
            for (int j = 0; j < 2; ++j) {
                int f = lane + 64 * j;               // covers AD/4 = 128
                float4 w4 = wr[f];
                float4 v4 = vv[f];
                acc += (double)w4.x * v4.x + (double)w4.y * v4.y
                     + (double)w4.z * v4.z + (double)w4.w * v4.w;
            }
            #pragma unroll
            for (int off = 32; off > 0; off >>= 1) acc += __shfl_down(acc, off);
            if (lane == 0) wv_eff[h] = (float)acc;
        }
    } else if (t < 64) {
        int lane = t;
        const float4* br = (const float4*)bk;
        const float4* vv = (const float4*)Wv;
        double acc = 0.0;
        #pragma unroll
        for (int j = 0; j < 2; ++j) {
            int f = lane + 64 * j;
            float4 b4 = br[f];
            float4 v4 = vv[f];
            acc += (double)b4.x * v4.x + (double)b4.y * v4.y
                 + (double)b4.z * v4.z + (double)b4.w * v4.w;
        }
        #pragma unroll
        for (int off = 32; off > 0; off >>= 1) acc += __shfl_down(acc, off);
        if (lane == 0) c_v[0] = (float)(acc + (double)bv[0]);
    }
}

// =====================================================================
// KM (merged k2+k3): 256 blocks x 512 threads; b = bid>>3, slice j = bid&7.
//   Phase A: s_q[b][:] into LDS (reduce partial over QCH chunks).
//   Phase B: FULL qsum[b][:] into LDS — computed redundantly (bitwise-
//            identically) by all 8 sibling blocks; no cross-block dep.
//   Phase C: wk_eff[b][h] = qsum·Wk[h,:] for h in [j*128,(j+1)*128).
// =====================================================================
__global__ void __launch_bounds__(512)
kM_mid(const float* __restrict__ partial, const float* __restrict__ Wq,
       const float* __restrict__ bq, const float* __restrict__ Wk,
       float* __restrict__ wk_eff) {
    __shared__ float sq[HD];     // 4 KB
    __shared__ float qs[AD];     // 2 KB
    const int bid = blockIdx.x;
    const int b = bid >> 3, j = bid & 7;
    const int t = threadIdx.x;   // 512

    // Phase A: 512 threads x 2 elements cover HD=1024
    #pragma unroll
    for (int c = 0; c < 2; ++c) {
        int h = t + c * 512;
        float acc = 0.f;
        #pragma unroll 4
        for (int qc = 0; qc < QCH; ++qc)
            acc += partial[((size_t)qc * NB + b) * HD + h];
        sq[h] = acc;
    }
    __syncthreads();

    // Phase B: thread t -> column a = t of Wq (coalesced across lanes per h)
    {
        const float* wp = Wq + t;
        double c0 = 0.0, c1 = 0.0, c2 = 0.0, c3 = 0.0;
        for (int h = 0; h < HD; h += 4) {
            c0 += (double)sq[h]     * wp[(size_t)h * AD];
            c1 += (double)sq[h + 1] * wp[(size_t)(h + 1) * AD];
            c2 += (double)sq[h + 2] * wp[(size_t)(h + 2) * AD];
            c3 += (double)sq[h + 3] * wp[(size_t)(h + 3) * AD];
        }
        qs[t] = (float)(((c0 + c1) + (c2 + c3)) + (double)LQ * (double)bq[t]);
    }
    __syncthreads();

    // Phase C: 8 waves x 16 rows each (2 in flight), slice of 128 h-rows
    int w = t >> 6, lane = t & 63;
    const float4* qs4 = (const float4*)qs;
    int h0base = j * 128 + w * 16;
    for (int r = 0; r < 16; r += 2) {
        int h0 = h0base + r;
        const float4* r0 = (const float4*)(Wk + (size_t)h0 * AD);
        const float4* r1 = (const float4*)(Wk + (size_t)(h0 + 1) * AD);
        double a0 = 0.0, a1 = 0.0;
        #pragma unroll
        for (int jj = 0; jj < 2; ++jj) {
            int f = lane + 64 * jj;
            float4 w0 = r0[f];
            float4 w1 = r1[f];
            float4 q4 = qs4[f];
            a0 += (double)w0.x * q4.x + (double)w0.y * q4.y
                + (double)w0.z * q4.z + (double)w0.w * q4.w;
            a1 += (double)w1.x * q4.x + (double)w1.y * q4.y
                + (double)w1.z * q4.z + (double)w1.w * q4.w;
        }
        #pragma unroll
        for (int off = 32; off > 0; off >>= 1) {
            a0 += __shfl_down(a0, off);
            a1 += __shfl_down(a1, off);
        }
        if (lane == 0) {
            wk_eff[(size_t)b * HD + h0]     = (float)a0;
            wk_eff[(size_t)b * HD + h0 + 1] = (float)a1;
        }
    }
}

// =====================================================================
// K4: 2048 blocks, 32 keys each, 4 rows in flight, non-temporal key loads:
//   scores = key·wk_eff[b], vvals = key·wv_eff + c_v (round-13 proven)
// =====================================================================
__global__ void __launch_bounds__(256)
k4_scores(const float* __restrict__ key, const float* __restrict__ wk_eff,
          const float* __restrict__ wv_eff, const float* __restrict__ c_v,
          float* __restrict__ scores, float* __restrict__ vvals) {
    __shared__ float lwk[HD];
    __shared__ float lwv[HD];
    const int bid = blockIdx.x;
    const int b = bid >> 6;              // 64 blocks per batch
    const int k0 = (bid & 63) * 32;
    const int t = threadIdx.x;
    for (int i = t; i < HD; i += 256) {
        lwk[i] = wk_eff[(size_t)b * HD + i];
        lwv[i] = wv_eff[i];
    }
    __syncthreads();
    int w = t >> 6, lane = t & 63;
    double cv = (double)c_v[0];
    const vf4* lwk4 = (const vf4*)lwk;
    const vf4* lwv4 = (const vf4*)lwv;
    for (int rp = 0; rp < 2; ++rp) {
        int k = k0 + w * 8 + rp * 4;
        const vf4* kr0 = (const vf4*)(key + ((size_t)b * LK + k) * HD);
        const vf4* kr1 = kr0 + (HD / 4);
        const vf4* kr2 = kr0 + 2 * (HD / 4);
        const vf4* kr3 = kr0 + 3 * (HD / 4);
        double sc0 = 0.0, vv0 = 0.0, sc1 = 0.0, vv1 = 0.0;
        double sc2 = 0.0, vv2 = 0.0, sc3 = 0.0, vv3 = 0.0;
        #pragma unroll
        for (int jj = 0; jj < 4; ++jj) {
            int f = lane + 64 * jj;
            vf4 k0v = __builtin_nontemporal_load(&kr0[f]);
            vf4 k1v = __builtin_nontemporal_load(&kr1[f]);
            vf4 k2v = __builtin_nontemporal_load(&kr2[f]);
            vf4 k3v = __builtin_nontemporal_load(&kr3[f]);
            vf4 wk4 = lwk4[f];
            vf4 wv4 = lwv4[f];
            sc0 += (double)k0v[0] * wk4[0] + (double)k0v[1] * wk4[1]
                 + (double)k0v[2] * wk4[2] + (double)k0v[3] * wk4[3];
            vv0 += (double)k0v[0] * wv4[0] + (double)k0v[1] * wv4[1]
                 + (double)k0v[2] * wv4[2] + (double)k0v[3] * wv4[3];
            sc1 += (double)k1v[0] * wk4[0] + (double)k1v[1] * wk4[1]
                 + (double)k1v[2] * wk4[2] + (double)k1v[3] * wk4[3];
            vv1 += (double)k1v[0] * wv4[0] + (double)k1v[1] * wv4[1]
                 + (double)k1v[2] * wv4[2] + (double)k1v[3] * wv4[3];
            sc2 += (double)k2v[0] * wk4[0] + (double)k2v[1] * wk4[1]
                 + (double)k2v[2] * wk4[2] + (double)k2v[3] * wk4[3];
            vv2 += (double)k2v[0] * wv4[0] + (double)k2v[1] * wv4[1]
                 + (double)k2v[2] * wv4[2] + (double)k2v[3] * wv4[3];
            sc3 += (double)k3v[0] * wk4[0] + (double)k3v[1] * wk4[1]
                 + (double)k3v[2] * wk4[2] + (double)k3v[3] * wk4[3];
            vv3 += (double)k3v[0] * wv4[0] + (double)k3v[1] * wv4[1]
                 + (double)k3v[2] * wv4[2] + (double)k3v[3] * wv4[3];
        }
        #pragma unroll
        for (int off = 32; off > 0; off >>= 1) {
            sc0 += __shfl_down(sc0, off);
            vv0 += __shfl_down(vv0, off);
            sc1 += __shfl_down(sc1, off);
            vv1 += __shfl_down(vv1, off);
            sc2 += __shfl_down(sc2, off);
            vv2 += __shfl_down(vv2, off);
            sc3 += __shfl_down(sc3, off);
            vv3 += __shfl_down(vv3, off);
        }
        if (lane == 0) {
            size_t base = (size_t)b * LK + k;
            scores[base]     = (float)sc0;  vvals[base]     = (float)(vv0 + cv);
            scores[base + 1] = (float)sc1;  vvals[base + 1] = (float)(vv1 + cv);
            scores[base + 2] = (float)sc2;  vvals[base + 2] = (float)(vv2 + cv);
            scores[base + 3] = (float)sc3;  vvals[base + 3] = (float)(vv3 + cv);
        }
    }
}

// =====================================================================
// K5: per-batch softmax + weighted sum -> out[b] (round-9 proven)
// =====================================================================
__global__ void __launch_bounds__(256)
k5_softmax(const float* __restrict__ scores, const float* __restrict__ vvals,
           float* __restrict__ out) {
    int b = blockIdx.x;
    int t = threadIdx.x;
    __shared__ float smax_sh[4];
    __shared__ double num_sh[4], den_sh[4];
    const float* sr = scores + (size_t)b * LK;
    const float* vr = vvals  + (size_t)b * LK;
    float m = -INFINITY;
    for (int k = t; k < LK; k += 256) m = fmaxf(m, sr[k]);
    #pragma unroll
    for (int off = 32; off > 0; off >>= 1) m = fmaxf(m, __shfl_down(m, off));
    int w = t >> 6, lane = t & 63;
    if (lane == 0) smax_sh[w] = m;
    __syncthreads();
    float gm = fmaxf(fmaxf(smax_sh[0], smax_sh[1]), fmaxf(smax_sh[2], smax_sh[3]));
    double num = 0.0, den = 0.0;
    for (int k = t; k < LK; k += 256) {
        double e = exp((double)(sr[k] - gm));
        den += e;
        num += e * (double)vr[k];
    }
    #pragma unroll
    for (int off = 32; off > 0; off >>= 1) {
        num += __shfl_down(num, off);
        den += __shfl_down(den, off);
    }
    if (lane == 0) { num_sh[w] = num; den_sh[w] = den; }
    __syncthreads();
    if (t == 0) {
        double N = num_sh[0] + num_sh[1] + num_sh[2] + num_sh[3];
        double D = den_sh[0] + den_sh[1] + den_sh[2] + den_sh[3];
        out[b] = (float)(N / D);
    }
}

extern "C" void kernel_launch(void* const* d_in, const int* in_sizes, int n_in,
                              void* d_out, int out_size, void* d_ws, size_t ws_size,
                              hipStream_t stream) {
    const float* query = (const float*)d_in[0];
    const float* key   = (const float*)d_in[1];
    const float* Wq    = (const float*)d_in[2];
    const float* bq    = (const float*)d_in[3];
    const float* Wk    = (const float*)d_in[4];
    const float* bk    = (const float*)d_in[5];
    const float* Wv    = (const float*)d_in[6];
    const float* bv    = (const float*)d_in[7];
    float* out = (float*)d_out;

    float* ws = (float*)d_ws;
    size_t off = 0;
    float* partial = ws + off; off += (size_t)QCH * NB * HD;   // 8 MB
    float* wk_eff  = ws + off; off += (size_t)NB * HD;
    float* wv_eff  = ws + off; off += (size_t)HD;
    float* c_v     = ws + off; off += 1;
    float* scores  = ws + off; off += (size_t)NB * LK;
    float* vvals   = ws + off; off += (size_t)NB * LK;

    hipLaunchKernelGGL(k1_stream, dim3(NB * QCH + 16 + 1), dim3(256), 0, stream,
                       query, Wk, Wv, bk, bv, partial, wv_eff, c_v);
    hipLaunchKernelGGL(kM_mid, dim3(256), dim3(512), 0, stream,
                       partial, Wq, bq, Wk, wk_eff);
    hipLaunchKernelGGL(k4_scores, dim3(NB * (LK / 32)), dim3(256), 0, stream,
                       key, wk_eff, wv_eff, c_v, scores, vvals);
    hipLaunchKernelGGL(k5_softmax, dim3(NB), dim3(256), 0, stream,
                       scores, vvals, out);
}

// Round 15
// 149.163 us; speedup vs baseline: 1.0586x; 1.0586x over previous
//
#include <hip/hip_runtime.h>
#include <math.h>

#define NB 32
#define LQ 2048
#define LK 2048
#define HD 1024
#define AD 512
#define QCH 64   // q-chunks for first-stage query reduction (2048 stream blocks)

typedef float vf4 __attribute__((ext_vector_type(4)));

// =====================================================================
// K1: blocks 0..2047   : partial[b][qc][h] = sum over 32-row q-chunk
//                        (4 rows in flight, non-temporal loads)
//     blocks 2048..2063: wv_eff[h] = Wk[h,:]·Wv (wave-per-row)
//     block  2064      : c_v = bk·Wv + bv
// (round-13 proven; partial layout transposed to [b][qc][h])
// =====================================================================
__global__ void __launch_bounds__(256)
k1_stream(const float* __restrict__ query, const float* __restrict__ Wk,
          const float* __restrict__ Wv, const float* __restrict__ bk,
          const float* __restrict__ bv, float* __restrict__ partial,
          float* __restrict__ wv_eff, float* __restrict__ c_v) {
    const int bid = blockIdx.x;
    const int t = threadIdx.x;
    if (bid < NB * QCH) {
        int b = bid / QCH, qc = bid % QCH;
        const int QPC = LQ / QCH;        // 32 rows per chunk
        vf4 a0 = {0.f,0.f,0.f,0.f}, a1 = {0.f,0.f,0.f,0.f};
        vf4 a2 = {0.f,0.f,0.f,0.f}, a3 = {0.f,0.f,0.f,0.f};
        const vf4* src = (const vf4*)(query + ((size_t)b * LQ + (size_t)qc * QPC) * HD);
        for (int q = 0; q < QPC; q += 4) {
            vf4 v0 = __builtin_nontemporal_load(&src[(size_t)(q + 0) * (HD / 4) + t]);
            vf4 v1 = __builtin_nontemporal_load(&src[(size_t)(q + 1) * (HD / 4) + t]);
            vf4 v2 = __builtin_nontemporal_load(&src[(size_t)(q + 2) * (HD / 4) + t]);
            vf4 v3 = __builtin_nontemporal_load(&src[(size_t)(q + 3) * (HD / 4) + t]);
            a0 += v0; a1 += v1; a2 += v2; a3 += v3;
        }
        vf4 acc = (a0 + a1) + (a2 + a3);
        ((vf4*)(partial + ((size_t)b * QCH + qc) * HD))[t] = acc;
    } else if (bid < NB * QCH + 16) {
        int w = t >> 6, lane = t & 63;
        int gw = (bid - NB * QCH) * 4 + w;           // 0..63
        const float4* vv = (const float4*)Wv;
        for (int r = 0; r < 16; ++r) {
            int h = gw * 16 + r;
            const float4* wr = (const float4*)(Wk + (size_t)h * AD);
            double acc = 0.0;
            #pragma unroll
            for (int j = 0; j < 2; ++j) {
                int f = lane + 64 * j;               // covers AD/4 = 128
                float4 w4 = wr[f];
                float4 v4 = vv[f];
                acc += (double)w4.x * v4.x + (double)w4.y * v4.y
                     + (double)w4.z * v4.z + (double)w4.w * v4.w;
            }
            #pragma unroll
            for (int off = 32; off > 0; off >>= 1) acc += __shfl_down(acc, off);
            if (lane == 0) wv_eff[h] = (float)acc;
        }
    } else if (t < 64) {
        int lane = t;
        const float4* br = (const float4*)bk;
        const float4* vv = (const float4*)Wv;
        double acc = 0.0;
        #pragma unroll
        for (int j = 0; j < 2; ++j) {
            int f = lane + 64 * j;
            float4 b4 = br[f];
            float4 v4 = vv[f];
            acc += (double)b4.x * v4.x + (double)b4.y * v4.y
                 + (double)b4.z * v4.z + (double)b4.w * v4.w;
        }
        #pragma unroll
        for (int off = 32; off > 0; off >>= 1) acc += __shfl_down(acc, off);
        if (lane == 0) c_v[0] = (float)(acc + (double)bv[0]);
    }
}

// =====================================================================
// K2: 256 blocks: b = bid>>3, a-chunk of 64 = (bid&7)*64.
//   Phase A: s_q[b][:] into LDS (now reads ONE contiguous 256 KB region).
//   Phase B: qsum[b][a0..a0+63] = s_q·Wq[:,a] + LQ*bq[a].
// =====================================================================
__global__ void __launch_bounds__(256)
k2_qsum(const float* __restrict__ partial, const float* __restrict__ Wq,
        const float* __restrict__ bq, float* __restrict__ qsum) {
    __shared__ float sq[HD];
    __shared__ double red[4][64];
    int b = blockIdx.x >> 3;
    int a0 = (blockIdx.x & 7) * 64;
    int t = threadIdx.x;

    #pragma unroll
    for (int c = 0; c < 4; ++c) {
        int h = t + c * 256;
        float acc = 0.f;
        const float* pb = partial + (size_t)b * QCH * HD + h;
        #pragma unroll 4
        for (int qc = 0; qc < QCH; ++qc)
            acc += pb[(size_t)qc * HD];
        sq[h] = acc;
    }
    __syncthreads();

    int w = t >> 6, lane = t & 63;
    int a = a0 + lane;
    const float* wp = Wq + a;
    double c0 = 0.0, c1 = 0.0, c2 = 0.0, c3 = 0.0;
    int hbase = w * 256;
    for (int i = 0; i < 256; i += 4) {
        int h = hbase + i;
        c0 += (double)sq[h]     * wp[(size_t)h * AD];
        c1 += (double)sq[h + 1] * wp[(size_t)(h + 1) * AD];
        c2 += (double)sq[h + 2] * wp[(size_t)(h + 2) * AD];
        c3 += (double)sq[h + 3] * wp[(size_t)(h + 3) * AD];
    }
    red[w][lane] = ((c0 + c1) + (c2 + c3));
    __syncthreads();
    if (t < 64) {
        double s = red[0][t] + red[1][t] + red[2][t] + red[3][t];
        qsum[(size_t)b * AD + a0 + t] = (float)(s + (double)LQ * bq[a0 + t]);
    }
}

// =====================================================================
// K3: 2048 blocks x 4 waves, 4 rows per wave — ALL 4 in flight:
//   wk_eff[b][h] = qsum[b]·Wk[h,:]
// =====================================================================
__global__ void __launch_bounds__(256)
k3_weff(const float* __restrict__ qsum, const float* __restrict__ Wk,
        float* __restrict__ wk_eff) {
    int w = threadIdx.x >> 6, lane = threadIdx.x & 63;
    int widx = blockIdx.x * 4 + w;                   // 8192 waves
    int idx0 = widx * 4;                             // 4 rows, same b (HD%4==0)
    int b = idx0 >> 10, h0 = idx0 & (HD - 1);
    const float4* r0 = (const float4*)(Wk + (size_t)h0 * AD);
    const float4* r1 = (const float4*)(Wk + (size_t)(h0 + 1) * AD);
    const float4* r2 = (const float4*)(Wk + (size_t)(h0 + 2) * AD);
    const float4* r3 = (const float4*)(Wk + (size_t)(h0 + 3) * AD);
    const float4* qs = (const float4*)(qsum + (size_t)b * AD);
    double a0 = 0.0, a1 = 0.0, a2 = 0.0, a3 = 0.0;
    #pragma unroll
    for (int j = 0; j < 2; ++j) {
        int f = lane + 64 * j;
        float4 w0 = r0[f];
        float4 w1 = r1[f];
        float4 w2 = r2[f];
        float4 w3 = r3[f];
        float4 q4 = qs[f];
        a0 += (double)w0.x * q4.x + (double)w0.y * q4.y
            + (double)w0.z * q4.z + (double)w0.w * q4.w;
        a1 += (double)w1.x * q4.x + (double)w1.y * q4.y
            + (double)w1.z * q4.z + (double)w1.w * q4.w;
        a2 += (double)w2.x * q4.x + (double)w2.y * q4.y
            + (double)w2.z * q4.z + (double)w2.w * q4.w;
        a3 += (double)w3.x * q4.x + (double)w3.y * q4.y
            + (double)w3.z * q4.z + (double)w3.w * q4.w;
    }
    #pragma unroll
    for (int off = 32; off > 0; off >>= 1) {
        a0 += __shfl_down(a0, off);
        a1 += __shfl_down(a1, off);
        a2 += __shfl_down(a2, off);
        a3 += __shfl_down(a3, off);
    }
    if (lane == 0) {
        wk_eff[idx0]     = (float)a0;
        wk_eff[idx0 + 1] = (float)a1;
        wk_eff[idx0 + 2] = (float)a2;
        wk_eff[idx0 + 3] = (float)a3;
    }
}

// =====================================================================
// K4: 2048 blocks, 32 keys each, 4 rows in flight, non-temporal key loads:
//   scores = key·wk_eff[b], vvals = key·wv_eff + c_v (round-13 proven)
// =====================================================================
__global__ void __launch_bounds__(256)
k4_scores(const float* __restrict__ key, const float* __restrict__ wk_eff,
          const float* __restrict__ wv_eff, const float* __restrict__ c_v,
          float* __restrict__ scores, float* __restrict__ vvals) {
    __shared__ float lwk[HD];
    __shared__ float lwv[HD];
    const int bid = blockIdx.x;
    const int b = bid >> 6;              // 64 blocks per batch
    const int k0 = (bid & 63) * 32;
    const int t = threadIdx.x;
    for (int i = t; i < HD; i += 256) {
        lwk[i] = wk_eff[(size_t)b * HD + i];
        lwv[i] = wv_eff[i];
    }
    __syncthreads();
    int w = t >> 6, lane = t & 63;
    double cv = (double)c_v[0];
    const vf4* lwk4 = (const vf4*)lwk;
    const vf4* lwv4 = (const vf4*)lwv;
    for (int rp = 0; rp < 2; ++rp) {
        int k = k0 + w * 8 + rp * 4;
        const vf4* kr0 = (const vf4*)(key + ((size_t)b * LK + k) * HD);
        const vf4* kr1 = kr0 + (HD / 4);
        const vf4* kr2 = kr0 + 2 * (HD / 4);
        const vf4* kr3 = kr0 + 3 * (HD / 4);
        double sc0 = 0.0, vv0 = 0.0, sc1 = 0.0, vv1 = 0.0;
        double sc2 = 0.0, vv2 = 0.0, sc3 = 0.0, vv3 = 0.0;
        #pragma unroll
        for (int jj = 0; jj < 4; ++jj) {
            int f = lane + 64 * jj;
            vf4 k0v = __builtin_nontemporal_load(&kr0[f]);
            vf4 k1v = __builtin_nontemporal_load(&kr1[f]);
            vf4 k2v = __builtin_nontemporal_load(&kr2[f]);
            vf4 k3v = __builtin_nontemporal_load(&kr3[f]);
            vf4 wk4 = lwk4[f];
            vf4 wv4 = lwv4[f];
            sc0 += (double)k0v[0] * wk4[0] + (double)k0v[1] * wk4[1]
                 + (double)k0v[2] * wk4[2] + (double)k0v[3] * wk4[3];
            vv0 += (double)k0v[0] * wv4[0] + (double)k0v[1] * wv4[1]
                 + (double)k0v[2] * wv4[2] + (double)k0v[3] * wv4[3];
            sc1 += (double)k1v[0] * wk4[0] + (double)k1v[1] * wk4[1]
                 + (double)k1v[2] * wk4[2] + (double)k1v[3] * wk4[3];
            vv1 += (double)k1v[0] * wv4[0] + (double)k1v[1] * wv4[1]
                 + (double)k1v[2] * wv4[2] + (double)k1v[3] * wv4[3];
            sc2 += (double)k2v[0] * wk4[0] + (double)k2v[1] * wk4[1]
                 + (double)k2v[2] * wk4[2] + (double)k2v[3] * wk4[3];
            vv2 += (double)k2v[0] * wv4[0] + (double)k2v[1] * wv4[1]
                 + (double)k2v[2] * wv4[2] + (double)k2v[3] * wv4[3];
            sc3 += (double)k3v[0] * wk4[0] + (double)k3v[1] * wk4[1]
                 + (double)k3v[2] * wk4[2] + (double)k3v[3] * wk4[3];
            vv3 += (double)k3v[0] * wv4[0] + (double)k3v[1] * wv4[1]
                 + (double)k3v[2] * wv4[2] + (double)k3v[3] * wv4[3];
        }
        #pragma unroll
        for (int off = 32; off > 0; off >>= 1) {
            sc0 += __shfl_down(sc0, off);
            vv0 += __shfl_down(vv0, off);
            sc1 += __shfl_down(sc1, off);
            vv1 += __shfl_down(vv1, off);
            sc2 += __shfl_down(sc2, off);
            vv2 += __shfl_down(vv2, off);
            sc3 += __shfl_down(sc3, off);
            vv3 += __shfl_down(vv3, off);
        }
        if (lane == 0) {
            size_t base = (size_t)b * LK + k;
            scores[base]     = (float)sc0;  vvals[base]     = (float)(vv0 + cv);
            scores[base + 1] = (float)sc1;  vvals[base + 1] = (float)(vv1 + cv);
            scores[base + 2] = (float)sc2;  vvals[base + 2] = (float)(vv2 + cv);
            scores[base + 3] = (float)sc3;  vvals[base + 3] = (float)(vv3 + cv);
        }
    }
}

// =====================================================================
// K5: per-batch softmax + weighted sum -> out[b] (round-9 proven)
// =====================================================================
__global__ void __launch_bounds__(256)
k5_softmax(const float* __restrict__ scores, const float* __restrict__ vvals,
           float* __restrict__ out) {
    int b = blockIdx.x;
    int t = threadIdx.x;
    __shared__ float smax_sh[4];
    __shared__ double num_sh[4], den_sh[4];
    const float* sr = scores + (size_t)b * LK;
    const float* vr = vvals  + (size_t)b * LK;
    float m = -INFINITY;
    for (int k = t; k < LK; k += 256) m = fmaxf(m, sr[k]);
    #pragma unroll
    for (int off = 32; off > 0; off >>= 1) m = fmaxf(m, __shfl_down(m, off));
    int w = t >> 6, lane = t & 63;
    if (lane == 0) smax_sh[w] = m;
    __syncthreads();
    float gm = fmaxf(fmaxf(smax_sh[0], smax_sh[1]), fmaxf(smax_sh[2], smax_sh[3]));
    double num = 0.0, den = 0.0;
    for (int k = t; k < LK; k += 256) {
        double e = exp((double)(sr[k] - gm));
        den += e;
        num += e * (double)vr[k];
    }
    #pragma unroll
    for (int off = 32; off > 0; off >>= 1) {
        num += __shfl_down(num, off);
        den += __shfl_down(den, off);
    }
    if (lane == 0) { num_sh[w] = num; den_sh[w] = den; }
    __syncthreads();
    if (t == 0) {
        double N = num_sh[0] + num_sh[1] + num_sh[2] + num_sh[3];
        double D = den_sh[0] + den_sh[1] + den_sh[2] + den_sh[3];
        out[b] = (float)(N / D);
    }
}

extern "C" void kernel_launch(void* const* d_in, const int* in_sizes, int n_in,
                              void* d_out, int out_size, void* d_ws, size_t ws_size,
                              hipStream_t stream) {
    const float* query = (const float*)d_in[0];
    const float* key   = (const float*)d_in[1];
    const float* Wq    = (const float*)d_in[2];
    const float* bq    = (const float*)d_in[3];
    const float* Wk    = (const float*)d_in[4];
    const float* bk    = (const float*)d_in[5];
    const float* Wv    = (const float*)d_in[6];
    const float* bv    = (const float*)d_in[7];
    float* out = (float*)d_out;

    float* ws = (float*)d_ws;
    size_t off = 0;
    float* partial = ws + off; off += (size_t)NB * QCH * HD;   // 8 MB, [b][qc][h]
    float* qsum    = ws + off; off += (size_t)NB * AD;
    float* wk_eff  = ws + off; off += (size_t)NB * HD;
    float* wv_eff  = ws + off; off += (size_t)HD;
    float* c_v     = ws + off; off += 1;
    float* scores  = ws + off; off += (size_t)NB * LK;
    float* vvals   = ws + off; off += (size_t)NB * LK;

    hipLaunchKernelGGL(k1_stream, dim3(NB * QCH + 16 + 1), dim3(256), 0, stream,
                       query, Wk, Wv, bk, bv, partial, wv_eff, c_v);
    hipLaunchKernelGGL(k2_qsum, dim3(256), dim3(256), 0, stream,
                       partial, Wq, bq, qsum);
    hipLaunchKernelGGL(k3_weff, dim3(2048), dim3(256), 0, stream,
                       qsum, Wk, wk_eff);
    hipLaunchKernelGGL(k4_scores, dim3(NB * (LK / 32)), dim3(256), 0, stream,
                       key, wk_eff, wv_eff, c_v, scores, vvals);
    hipLaunchKernelGGL(k5_softmax, dim3(NB), dim3(256), 0, stream,
                       scores, vvals, out);
}

// Round 16
// 147.914 us; speedup vs baseline: 1.0675x; 1.0084x over previous
//
#include <hip/hip_runtime.h>
#include <math.h>

#define NB 32
#define LQ 2048
#define LK 2048
#define HD 1024
#define AD 512
#define QCH 64   // q-chunks for first-stage query reduction (2048 stream blocks)

typedef float vf4 __attribute__((ext_vector_type(4)));

// =====================================================================
// K1: blocks 0..2047   : partial[qc][b][h] = sum over 32-row q-chunk
//                        (4 rows in flight, non-temporal loads)
//     blocks 2048..2063: wv_eff[h] = Wk[h,:]·Wv (wave-per-row)
//     block  2064      : c_v = bk·Wv + bv
// (round-13 champion, byte-identical)
// =====================================================================
__global__ void __launch_bounds__(256)
k1_stream(const float* __restrict__ query, const float* __restrict__ Wk,
          const float* __restrict__ Wv, const float* __restrict__ bk,
          const float* __restrict__ bv, float* __restrict__ partial,
          float* __restrict__ wv_eff, float* __restrict__ c_v) {
    const int bid = blockIdx.x;
    const int t = threadIdx.x;
    if (bid < NB * QCH) {
        int b = bid / QCH, qc = bid % QCH;
        const int QPC = LQ / QCH;        // 32 rows per chunk
        vf4 a0 = {0.f,0.f,0.f,0.f}, a1 = {0.f,0.f,0.f,0.f};
        vf4 a2 = {0.f,0.f,0.f,0.f}, a3 = {0.f,0.f,0.f,0.f};
        const vf4* src = (const vf4*)(query + ((size_t)b * LQ + (size_t)qc * QPC) * HD);
        for (int q = 0; q < QPC; q += 4) {
            vf4 v0 = __builtin_nontemporal_load(&src[(size_t)(q + 0) * (HD / 4) + t]);
            vf4 v1 = __builtin_nontemporal_load(&src[(size_t)(q + 1) * (HD / 4) + t]);
            vf4 v2 = __builtin_nontemporal_load(&src[(size_t)(q + 2) * (HD / 4) + t]);
            vf4 v3 = __builtin_nontemporal_load(&src[(size_t)(q + 3) * (HD / 4) + t]);
            a0 += v0; a1 += v1; a2 += v2; a3 += v3;
        }
        vf4 acc = (a0 + a1) + (a2 + a3);
        ((vf4*)(partial + ((size_t)qc * NB + b) * HD))[t] = acc;
    } else if (bid < NB * QCH + 16) {
        int w = t >> 6, lane = t & 63;
        int gw = (bid - NB * QCH) * 4 + w;           // 0..63
        const float4* vv = (const float4*)Wv;
        for (int r = 0; r < 16; ++r) {
            int h = gw * 16 + r;
            const float4* wr = (const float4*)(Wk + (size_t)h * AD);
            double acc = 0.0;
            #pragma unroll
            for (int j = 0; j < 2; ++j) {
                int f = lane + 64 * j;               // covers AD/4 = 128
                float4 w4 = wr[f];
                float4 v4 = vv[f];
                acc += (double)w4.x * v4.x + (double)w4.y * v4.y
                     + (double)w4.z * v4.z + (double)w4.w * v4.w;
            }
            #pragma unroll
            for (int off = 32; off > 0; off >>= 1) acc += __shfl_down(acc, off);
            if (lane == 0) wv_eff[h] = (float)acc;
        }
    } else if (t < 64) {
        int lane = t;
        const float4* br = (const float4*)bk;
        const float4* vv = (const float4*)Wv;
        double acc = 0.0;
        #pragma unroll
        for (int j = 0; j < 2; ++j) {
            int f = lane + 64 * j;
            float4 b4 = br[f];
            float4 v4 = vv[f];
            acc += (double)b4.x * v4.x + (double)b4.y * v4.y
                 + (double)b4.z * v4.z + (double)b4.w * v4.w;
        }
        #pragma unroll
        for (int off = 32; off > 0; off >>= 1) acc += __shfl_down(acc, off);
        if (lane == 0) c_v[0] = (float)(acc + (double)bv[0]);
    }
}

// =====================================================================
// K2: 256 blocks: b = bid>>3, a-chunk of 64 = (bid&7)*64.
//   Phase A: s_q[b][:] into LDS; Phase B: qsum chunk. (proven round-3/9/13)
// =====================================================================
__global__ void __launch_bounds__(256)
k2_qsum(const float* __restrict__ partial, const float* __restrict__ Wq,
        const float* __restrict__ bq, float* __restrict__ qsum) {
    __shared__ float sq[HD];
    __shared__ double red[4][64];
    int b = blockIdx.x >> 3;
    int a0 = (blockIdx.x & 7) * 64;
    int t = threadIdx.x;

    #pragma unroll
    for (int c = 0; c < 4; ++c) {
        int h = t + c * 256;
        float acc = 0.f;
        #pragma unroll 4
        for (int qc = 0; qc < QCH; ++qc)
            acc += partial[((size_t)qc * NB + b) * HD + h];
        sq[h] = acc;
    }
    __syncthreads();

    int w = t >> 6, lane = t & 63;
    int a = a0 + lane;
    const float* wp = Wq + a;
    double c0 = 0.0, c1 = 0.0, c2 = 0.0, c3 = 0.0;
    int hbase = w * 256;
    for (int i = 0; i < 256; i += 4) {
        int h = hbase + i;
        c0 += (double)sq[h]     * wp[(size_t)h * AD];
        c1 += (double)sq[h + 1] * wp[(size_t)(h + 1) * AD];
        c2 += (double)sq[h + 2] * wp[(size_t)(h + 2) * AD];
        c3 += (double)sq[h + 3] * wp[(size_t)(h + 3) * AD];
    }
    red[w][lane] = ((c0 + c1) + (c2 + c3));
    __syncthreads();
    if (t < 64) {
        double s = red[0][t] + red[1][t] + red[2][t] + red[3][t];
        qsum[(size_t)b * AD + a0 + t] = (float)(s + (double)LQ * bq[a0 + t]);
    }
}

// =====================================================================
// K3: 2048 blocks x 4 waves, 4 rows per wave (2 in flight):
//   wk_eff[b][h] = qsum[b]·Wk[h,:]   (proven round-9/13)
// =====================================================================
__global__ void __launch_bounds__(256)
k3_weff(const float* __restrict__ qsum, const float* __restrict__ Wk,
        float* __restrict__ wk_eff) {
    int w = threadIdx.x >> 6, lane = threadIdx.x & 63;
    int widx = blockIdx.x * 4 + w;                   // 8192 waves
    int base = widx * 4;                             // 4 rows each
    for (int r = 0; r < 4; r += 2) {
        int idx0 = base + r;                         // 0..32767
        int b = idx0 >> 10, h0 = idx0 & (HD - 1);
        const float4* r0 = (const float4*)(Wk + (size_t)h0 * AD);
        const float4* r1 = (const float4*)(Wk + (size_t)(h0 + 1) * AD);
        const float4* qs = (const float4*)(qsum + (size_t)b * AD);
        double a0 = 0.0, a1 = 0.0;
        #pragma unroll
        for (int j = 0; j < 2; ++j) {
            int f = lane + 64 * j;
            float4 w0 = r0[f];
            float4 w1 = r1[f];
            float4 q4 = qs[f];
            a0 += (double)w0.x * q4.x + (double)w0.y * q4.y
                + (double)w0.z * q4.z + (double)w0.w * q4.w;
            a1 += (double)w1.x * q4.x + (double)w1.y * q4.y
                + (double)w1.z * q4.z + (double)w1.w * q4.w;
        }
        #pragma unroll
        for (int off = 32; off > 0; off >>= 1) {
            a0 += __shfl_down(a0, off);
            a1 += __shfl_down(a1, off);
        }
        if (lane == 0) {
            wk_eff[idx0]     = (float)a0;
            wk_eff[idx0 + 1] = (float)a1;
        }
    }
}

// =====================================================================
// K4: 2048 blocks, 32 keys each, 4 rows in flight, non-temporal key loads:
//   scores = key·wk_eff[b], vvals = key·wv_eff + c_v (round-13 champion)
// =====================================================================
__global__ void __launch_bounds__(256)
k4_scores(const float* __restrict__ key, const float* __restrict__ wk_eff,
          const float* __restrict__ wv_eff, const float* __restrict__ c_v,
          float* __restrict__ scores, float* __restrict__ vvals) {
    __shared__ float lwk[HD];
    __shared__ float lwv[HD];
    const int bid = blockIdx.x;
    const int b = bid >> 6;              // 64 blocks per batch
    const int k0 = (bid & 63) * 32;
    const int t = threadIdx.x;
    for (int i = t; i < HD; i += 256) {
        lwk[i] = wk_eff[(size_t)b * HD + i];
        lwv[i] = wv_eff[i];
    }
    __syncthreads();
    int w = t >> 6, lane = t & 63;
    double cv = (double)c_v[0];
    const vf4* lwk4 = (const vf4*)lwk;
    const vf4* lwv4 = (const vf4*)lwv;
    for (int rp = 0; rp < 2; ++rp) {
        int k = k0 + w * 8 + rp * 4;
        const vf4* kr0 = (const vf4*)(key + ((size_t)b * LK + k) * HD);
        const vf4* kr1 = kr0 + (HD / 4);
        const vf4* kr2 = kr0 + 2 * (HD / 4);
        const vf4* kr3 = kr0 + 3 * (HD / 4);
        double sc0 = 0.0, vv0 = 0.0, sc1 = 0.0, vv1 = 0.0;
        double sc2 = 0.0, vv2 = 0.0, sc3 = 0.0, vv3 = 0.0;
        #pragma unroll
        for (int jj = 0; jj < 4; ++jj) {
            int f = lane + 64 * jj;
            vf4 k0v = __builtin_nontemporal_load(&kr0[f]);
            vf4 k1v = __builtin_nontemporal_load(&kr1[f]);
            vf4 k2v = __builtin_nontemporal_load(&kr2[f]);
            vf4 k3v = __builtin_nontemporal_load(&kr3[f]);
            vf4 wk4 = lwk4[f];
            vf4 wv4 = lwv4[f];
            sc0 += (double)k0v[0] * wk4[0] + (double)k0v[1] * wk4[1]
                 + (double)k0v[2] * wk4[2] + (double)k0v[3] * wk4[3];
            vv0 += (double)k0v[0] * wv4[0] + (double)k0v[1] * wv4[1]
                 + (double)k0v[2] * wv4[2] + (double)k0v[3] * wv4[3];
            sc1 += (double)k1v[0] * wk4[0] + (double)k1v[1] * wk4[1]
                 + (double)k1v[2] * wk4[2] + (double)k1v[3] * wk4[3];
            vv1 += (double)k1v[0] * wv4[0] + (double)k1v[1] * wv4[1]
                 + (double)k1v[2] * wv4[2] + (double)k1v[3] * wv4[3];
            sc2 += (double)k2v[0] * wk4[0] + (double)k2v[1] * wk4[1]
                 + (double)k2v[2] * wk4[2] + (double)k2v[3] * wk4[3];
            vv2 += (double)k2v[0] * wv4[0] + (double)k2v[1] * wv4[1]
                 + (double)k2v[2] * wv4[2] + (double)k2v[3] * wv4[3];
            sc3 += (double)k3v[0] * wk4[0] + (double)k3v[1] * wk4[1]
                 + (double)k3v[2] * wk4[2] + (double)k3v[3] * wk4[3];
            vv3 += (double)k3v[0] * wv4[0] + (double)k3v[1] * wv4[1]
                 + (double)k3v[2] * wv4[2] + (double)k3v[3] * wv4[3];
        }
        #pragma unroll
        for (int off = 32; off > 0; off >>= 1) {
            sc0 += __shfl_down(sc0, off);
            vv0 += __shfl_down(vv0, off);
            sc1 += __shfl_down(sc1, off);
            vv1 += __shfl_down(vv1, off);
            sc2 += __shfl_down(sc2, off);
            vv2 += __shfl_down(vv2, off);
            sc3 += __shfl_down(sc3, off);
            vv3 += __shfl_down(vv3, off);
        }
        if (lane == 0) {
            size_t base = (size_t)b * LK + k;
            scores[base]     = (float)sc0;  vvals[base]     = (float)(vv0 + cv);
            scores[base + 1] = (float)sc1;  vvals[base + 1] = (float)(vv1 + cv);
            scores[base + 2] = (float)sc2;  vvals[base + 2] = (float)(vv2 + cv);
            scores[base + 3] = (float)sc3;  vvals[base + 3] = (float)(vv3 + cv);
        }
    }
}

// =====================================================================
// K5: per-batch softmax + weighted sum -> out[b] (round-9 proven)
// =====================================================================
__global__ void __launch_bounds__(256)
k5_softmax(const float* __restrict__ scores, const float* __restrict__ vvals,
           float* __restrict__ out) {
    int b = blockIdx.x;
    int t = threadIdx.x;
    __shared__ float smax_sh[4];
    __shared__ double num_sh[4], den_sh[4];
    const float* sr = scores + (size_t)b * LK;
    const float* vr = vvals  + (size_t)b * LK;
    float m = -INFINITY;
    for (int k = t; k < LK; k += 256) m = fmaxf(m, sr[k]);
    #pragma unroll
    for (int off = 32; off > 0; off >>= 1) m = fmaxf(m, __shfl_down(m, off));
    int w = t >> 6, lane = t & 63;
    if (lane == 0) smax_sh[w] = m;
    __syncthreads();
    float gm = fmaxf(fmaxf(smax_sh[0], smax_sh[1]), fmaxf(smax_sh[2], smax_sh[3]));
    double num = 0.0, den = 0.0;
    for (int k = t; k < LK; k += 256) {
        double e = exp((double)(sr[k] - gm));
        den += e;
        num += e * (double)vr[k];
    }
    #pragma unroll
    for (int off = 32; off > 0; off >>= 1) {
        num += __shfl_down(num, off);
        den += __shfl_down(den, off);
    }
    if (lane == 0) { num_sh[w] = num; den_sh[w] = den; }
    __syncthreads();
    if (t == 0) {
        double N = num_sh[0] + num_sh[1] + num_sh[2] + num_sh[3];
        double D = den_sh[0] + den_sh[1] + den_sh[2] + den_sh[3];
        out[b] = (float)(N / D);
    }
}

extern "C" void kernel_launch(void* const* d_in, const int* in_sizes, int n_in,
                              void* d_out, int out_size, void* d_ws, size_t ws_size,
                              hipStream_t stream) {
    const float* query = (const float*)d_in[0];
    const float* key   = (const float*)d_in[1];
    const float* Wq    = (const float*)d_in[2];
    const float* bq    = (const float*)d_in[3];
    const float* Wk    = (const float*)d_in[4];
    const float* bk    = (const float*)d_in[5];
    const float* Wv    = (const float*)d_in[6];
    const float* bv    = (const float*)d_in[7];
    float* out = (float*)d_out;

    float* ws = (float*)d_ws;
    size_t off = 0;
    float* partial = ws + off; off += (size_t)QCH * NB * HD;   // 8 MB
    float* qsum    = ws + off; off += (size_t)NB * AD;
    float* wk_eff  = ws + off; off += (size_t)NB * HD;
    float* wv_eff  = ws + off; off += (size_t)HD;
    float* c_v     = ws + off; off += 1;
    float* scores  = ws + off; off += (size_t)NB * LK;
    float* vvals   = ws + off; off += (size_t)NB * LK;

    hipLaunchKernelGGL(k1_stream, dim3(NB * QCH + 16 + 1), dim3(256), 0, stream,
                       query, Wk, Wv, bk, bv, partial, wv_eff, c_v);
    hipLaunchKernelGGL(k2_qsum, dim3(256), dim3(256), 0, stream,
                       partial, Wq, bq, qsum);
    hipLaunchKernelGGL(k3_weff, dim3(2048), dim3(256), 0, stream,
                       qsum, Wk, wk_eff);
    hipLaunchKernelGGL(k4_scores, dim3(NB * (LK / 32)), dim3(256), 0, stream,
                       key, wk_eff, wv_eff, c_v, scores, vvals);
    hipLaunchKernelGGL(k5_softmax, dim3(NB), dim3(256), 0, stream,
                       scores, vvals, out);
}